// Round 1
// baseline (152.261 us; speedup 1.0000x reference)
//
#include <hip/hip_runtime.h>
#include <math.h>

// Problem constants (from reference)
#define N_PROP   1000
#define C_ALL    81          // classes incl. background
#define N_FG     80          // foreground classes
#define TOPK     100
#define SORTN    1024        // next pow2 >= N_PROP
#define IMG_WH   800.0f
#define SCORE_TH 0.05f
#define NMS_TH   0.5f
#define MIN_SZ   1.0f
#define BBOX_CLIP 4.135166556742356f   // log(1000/16)

// ---------------------------------------------------------------- kernel A
// Per-proposal softmax statistics: row max and sum(exp(x - max)).
__global__ void softmax_stats_kernel(const float* __restrict__ logits,
                                     float* __restrict__ smax,
                                     float* __restrict__ ssum) {
    int n = blockIdx.x * blockDim.x + threadIdx.x;
    if (n >= N_PROP) return;
    const float* row = logits + n * C_ALL;
    float m = row[0];
    #pragma unroll 9
    for (int c = 1; c < C_ALL; ++c) m = fmaxf(m, row[c]);
    float s = 0.0f;
    #pragma unroll 9
    for (int c = 0; c < C_ALL; ++c) s += expf(row[c] - m);
    smax[n] = m;
    ssum[n] = s;
}

// ---------------------------------------------------------------- kernel B
// Per (proposal, fg-class): softmax score, box decode, clip, validity mask.
// Writes class-major arrays for the per-class NMS kernel.
__global__ void decode_kernel(const float* __restrict__ logits,
                              const float* __restrict__ boxreg,
                              const float* __restrict__ prop,
                              const float* __restrict__ smax,
                              const float* __restrict__ ssum,
                              float* __restrict__ scoresC,   // [N_FG][N_PROP]
                              float* __restrict__ boxesC) {  // [N_FG][N_PROP][4]
    int idx = blockIdx.x * blockDim.x + threadIdx.x;
    if (idx >= N_PROP * N_FG) return;
    int n = idx / N_FG;
    int c = idx % N_FG;              // fg class c -> logit column c+1

    float logit = logits[n * C_ALL + (c + 1)];
    float score = expf(logit - smax[n]) / ssum[n];

    const float* p = prop + n * 4;
    float w  = p[2] - p[0];
    float h  = p[3] - p[1];
    float cx = p[0] + 0.5f * w;
    float cy = p[1] + 0.5f * h;

    const float* d = boxreg + n * (C_ALL * 4) + (c + 1) * 4;
    float dx = d[0] / 10.0f;
    float dy = d[1] / 10.0f;
    float dw = fminf(d[2] / 5.0f, BBOX_CLIP);
    float dh = fminf(d[3] / 5.0f, BBOX_CLIP);

    float pcx = dx * w + cx;
    float pcy = dy * h + cy;
    float pw  = expf(dw) * w;
    float ph  = expf(dh) * h;

    float x1 = pcx - 0.5f * pw;
    float y1 = pcy - 0.5f * ph;
    float x2 = pcx + 0.5f * pw;
    float y2 = pcy + 0.5f * ph;
    x1 = fminf(fmaxf(x1, 0.0f), IMG_WH);
    y1 = fminf(fmaxf(y1, 0.0f), IMG_WH);
    x2 = fminf(fmaxf(x2, 0.0f), IMG_WH);
    y2 = fminf(fmaxf(y2, 0.0f), IMG_WH);

    float bw = x2 - x1;
    float bh = y2 - y1;
    bool valid = (score >= SCORE_TH) && (bw >= MIN_SZ) && (bh >= MIN_SZ);

    scoresC[c * N_PROP + n] = valid ? score : -1.0f;
    float* ob = boxesC + (size_t)(c * N_PROP + n) * 4;
    ob[0] = x1; ob[1] = y1; ob[2] = x2; ob[3] = y2;
}

// ---------------------------------------------------------------- kernel C
// One block per class: bitonic sort (score desc, idx asc — matches stable
// argsort(-s)), then greedy NMS with parallel suppression. Kept boxes come
// out in descending-score order, so top_k(100) == first 100 kept.
__global__ __launch_bounds__(256) void nms_kernel(const float* __restrict__ scoresC,
                                                  const float* __restrict__ boxesC,
                                                  float* __restrict__ out) {
    __shared__ float s_s[SORTN];
    __shared__ int   s_i[SORTN];
    __shared__ float s_x1[SORTN], s_y1[SORTN], s_x2[SORTN], s_y2[SORTN], s_ar[SORTN];
    __shared__ unsigned char s_rem[SORTN];
    __shared__ int s_kept;

    const int c   = blockIdx.x;
    const int tid = threadIdx.x;

    // Output layout (floats): boxes[80][100][4] | scores[80][100] |
    // labels[80][100] | valid[80][100]
    const int OFF_SCORES = N_FG * TOPK * 4;          // 32000
    const int OFF_LABELS = OFF_SCORES + N_FG * TOPK; // 40000
    const int OFF_VALID  = OFF_LABELS + N_FG * TOPK; // 48000

    // Zero this class's output slice (harness poisons d_out each call).
    for (int t = tid; t < TOPK * 4; t += 256) out[c * TOPK * 4 + t] = 0.0f;
    for (int t = tid; t < TOPK; t += 256) {
        out[OFF_SCORES + c * TOPK + t] = 0.0f;
        out[OFF_LABELS + c * TOPK + t] = 0.0f;
        out[OFF_VALID  + c * TOPK + t] = 0.0f;
    }

    // Load scores (pad to 1024 with sentinel below the -0.5 validity cut).
    for (int t = tid; t < SORTN; t += 256) {
        s_s[t]   = (t < N_PROP) ? scoresC[c * N_PROP + t] : -2.0f;
        s_i[t]   = t;
        s_rem[t] = 0;
    }
    if (tid == 0) s_kept = 0;
    __syncthreads();

    // Bitonic sort: "less" = (higher score) or (equal score, lower index).
    for (int k = 2; k <= SORTN; k <<= 1) {
        for (int j = k >> 1; j > 0; j >>= 1) {
            for (int i = tid; i < SORTN; i += 256) {
                int ixj = i ^ j;
                if (ixj > i) {
                    float sa = s_s[i], sb = s_s[ixj];
                    int   ia = s_i[i], ib = s_i[ixj];
                    bool b_before_a = (sb > sa) || (sb == sa && ib < ia);
                    bool dir = ((i & k) == 0);
                    if (b_before_a == dir) {
                        s_s[i] = sb; s_s[ixj] = sa;
                        s_i[i] = ib; s_i[ixj] = ia;
                    }
                }
            }
            __syncthreads();
        }
    }

    // Gather boxes for valid sorted entries.
    for (int t = tid; t < SORTN; t += 256) {
        if (s_s[t] > -0.5f) {
            const float* b = boxesC + (size_t)(c * N_PROP + s_i[t]) * 4;
            float x1 = b[0], y1 = b[1], x2 = b[2], y2 = b[3];
            s_x1[t] = x1; s_y1[t] = y1; s_x2[t] = x2; s_y2[t] = y2;
            s_ar[t] = (x2 - x1) * (y2 - y1);
        }
    }
    __syncthreads();

    // Greedy NMS. All branch conditions below are same-address LDS reads,
    // uniform across the block; s_rem writes are fenced by the per-kept
    // __syncthreads before any re-read.
    for (int i = 0; i < SORTN; ++i) {
        if (s_s[i] <= -0.5f) break;      // sorted: rest are invalid
        if (s_rem[i]) continue;          // suppressed earlier

        if (tid == 0) {
            int k = s_kept;
            out[(c * TOPK + k) * 4 + 0] = s_x1[i];
            out[(c * TOPK + k) * 4 + 1] = s_y1[i];
            out[(c * TOPK + k) * 4 + 2] = s_x2[i];
            out[(c * TOPK + k) * 4 + 3] = s_y2[i];
            out[OFF_SCORES + c * TOPK + k] = s_s[i];
            out[OFF_LABELS + c * TOPK + k] = (float)(c + 1);
            out[OFF_VALID  + c * TOPK + k] = 1.0f;
            s_kept = k + 1;
        }

        float x1i = s_x1[i], y1i = s_y1[i], x2i = s_x2[i], y2i = s_y2[i];
        float ai  = s_ar[i];
        for (int jj = i + 1 + tid; jj < SORTN; jj += 256) {
            if (s_s[jj] <= -0.5f) break;   // sorted: rest invalid (per-thread)
            if (s_rem[jj]) continue;
            float lx = fmaxf(x1i, s_x1[jj]);
            float ly = fmaxf(y1i, s_y1[jj]);
            float rx = fminf(x2i, s_x2[jj]);
            float ry = fminf(y2i, s_y2[jj]);
            float iw = fmaxf(rx - lx, 0.0f);
            float ih = fmaxf(ry - ly, 0.0f);
            float inter = iw * ih;
            float iou = inter / (ai + s_ar[jj] - inter + 1e-9f);
            if (iou > NMS_TH) s_rem[jj] = 1;
        }
        __syncthreads();                 // publish s_rem + s_kept
        if (s_kept >= TOPK) break;       // uniform read after barrier
    }
}

extern "C" void kernel_launch(void* const* d_in, const int* in_sizes, int n_in,
                              void* d_out, int out_size, void* d_ws, size_t ws_size,
                              hipStream_t stream) {
    const float* class_logit = (const float*)d_in[0];   // [1000][81]
    const float* box_reg     = (const float*)d_in[1];   // [1000][324]
    const float* proposal    = (const float*)d_in[2];   // [1000][4]
    float* out = (float*)d_out;                         // 56000 floats

    // Workspace layout (floats)
    float* ws      = (float*)d_ws;
    float* smax    = ws;                        // 1000
    float* ssum    = smax + N_PROP;             // 1000
    float* scoresC = ssum + N_PROP;             // 80 * 1000
    float* boxesC  = scoresC + N_FG * N_PROP;   // 80 * 1000 * 4

    softmax_stats_kernel<<<(N_PROP + 255) / 256, 256, 0, stream>>>(class_logit, smax, ssum);

    int nb = (N_PROP * N_FG + 255) / 256;
    decode_kernel<<<nb, 256, 0, stream>>>(class_logit, box_reg, proposal,
                                          smax, ssum, scoresC, boxesC);

    nms_kernel<<<N_FG, 256, 0, stream>>>(scoresC, boxesC, out);
}

// Round 2
// 148.401 us; speedup vs baseline: 1.0260x; 1.0260x over previous
//
#include <hip/hip_runtime.h>
#include <math.h>

// Problem constants (from reference)
#define N_PROP   1000
#define C_ALL    81
#define N_FG     80
#define TOPK     100
#define CAP      1024        // max compacted entries (>= N_PROP rounded up)
#define IMG_WH   800.0f
#define SCORE_TH 0.05f
#define NMS_TH   0.5f
#define MIN_SZ   1.0f
#define BBOX_CLIP 4.135166556742356f   // log(1000/16)

typedef unsigned long long u64;

// One block per foreground class. Fully fused:
// softmax -> decode -> filter -> compact -> sort(V) -> NMS -> top-100 write.
__global__ __launch_bounds__(256) void roihead_kernel(
    const float* __restrict__ logits,   // [1000][81]
    const float* __restrict__ boxreg,   // [1000][324]
    const float* __restrict__ prop,     // [1000][4]
    float* __restrict__ out)            // 56000 floats
{
    // Compaction-order arrays (indexed by slot)
    __shared__ u64   s_key[CAP];
    __shared__ float cx1[CAP], cy1[CAP], cx2[CAP], cy2[CAP], car[CAP];
    // Sorted-order arrays
    __shared__ float sx1[CAP], sy1[CAP], sx2[CAP], sy2[CAP], sar[CAP];
    __shared__ u64   s_mask[256 * 4];   // suppression bit-matrix (V<=256 path)
    __shared__ u64   s_keep[4];
    __shared__ unsigned char s_rem[CAP]; // fallback path
    __shared__ int   s_cnt, s_emit;

    const int c   = blockIdx.x;
    const int tid = threadIdx.x;
    const int col = c + 1;              // logit / boxreg column

    const int OFF_SCORES = N_FG * TOPK * 4;          // 32000
    const int OFF_LABELS = OFF_SCORES + N_FG * TOPK; // 40000
    const int OFF_VALID  = OFF_LABELS + N_FG * TOPK; // 48000

    // Zero this class's output slice (harness poisons d_out every call).
    for (int t = tid; t < TOPK * 4; t += 256) out[c * TOPK * 4 + t] = 0.0f;
    for (int t = tid; t < TOPK; t += 256) {
        out[OFF_SCORES + c * TOPK + t] = 0.0f;
        out[OFF_LABELS + c * TOPK + t] = 0.0f;
        out[OFF_VALID  + c * TOPK + t] = 0.0f;
    }
    if (tid == 0) { s_cnt = 0; s_emit = 0; }
    __syncthreads();

    // ---- Phase 1: softmax + decode + filter + compact -------------------
    for (int n = tid; n < N_PROP; n += 256) {
        const float* row = logits + n * C_ALL;
        float m = row[0];
        for (int k = 1; k < C_ALL; ++k) m = fmaxf(m, row[k]);
        float ssum = 0.0f;
        for (int k = 0; k < C_ALL; ++k) ssum += expf(row[k] - m);
        float score = expf(row[col] - m) / ssum;

        const float* p = prop + n * 4;
        float w  = p[2] - p[0];
        float h  = p[3] - p[1];
        float pcx0 = p[0] + 0.5f * w;
        float pcy0 = p[1] + 0.5f * h;

        const float* d = boxreg + n * (C_ALL * 4) + col * 4;
        float dx = d[0] / 10.0f;
        float dy = d[1] / 10.0f;
        float dw = fminf(d[2] / 5.0f, BBOX_CLIP);
        float dh = fminf(d[3] / 5.0f, BBOX_CLIP);

        float pcx = dx * w + pcx0;
        float pcy = dy * h + pcy0;
        float pw  = expf(dw) * w;
        float ph  = expf(dh) * h;

        float x1 = fminf(fmaxf(pcx - 0.5f * pw, 0.0f), IMG_WH);
        float y1 = fminf(fmaxf(pcy - 0.5f * ph, 0.0f), IMG_WH);
        float x2 = fminf(fmaxf(pcx + 0.5f * pw, 0.0f), IMG_WH);
        float y2 = fminf(fmaxf(pcy + 0.5f * ph, 0.0f), IMG_WH);

        float bw = x2 - x1;
        float bh = y2 - y1;
        if (score >= SCORE_TH && bw >= MIN_SZ && bh >= MIN_SZ) {
            int slot = atomicAdd(&s_cnt, 1);
            // key: (score bits | 1023-idx | slot) -> descending-u64 sort
            // gives exactly (score desc, original index asc). Ties beyond
            // that are impossible (idx unique), so slot bits never decide.
            unsigned int fb = __float_as_uint(score);  // score>0 -> monotonic
            s_key[slot] = ((u64)fb << 20) | ((u64)(1023 - n) << 10) | (u64)slot;
            cx1[slot] = x1; cy1[slot] = y1; cx2[slot] = x2; cy2[slot] = y2;
            car[slot] = bw * bh;
        }
    }
    __syncthreads();

    const int V = s_cnt;
    if (V == 0) return;                 // outputs already zeroed

    // ---- Phase 2: bitonic sort of V entries (pad to pow2 with key 0) ----
    int VP2 = 1; while (VP2 < V) VP2 <<= 1;
    for (int t = V + tid; t < VP2; t += 256) s_key[t] = 0ull;
    __syncthreads();

    for (int k = 2; k <= VP2; k <<= 1) {
        for (int j = k >> 1; j > 0; j >>= 1) {
            for (int i = tid; i < VP2; i += 256) {
                int ixj = i ^ j;
                if (ixj > i) {
                    u64 a = s_key[i], b = s_key[ixj];
                    bool dir = ((i & k) == 0);   // descending region
                    if ((b > a) == dir) { s_key[i] = b; s_key[ixj] = a; }
                }
            }
            __syncthreads();
        }
    }

    // Gather coords into sorted order.
    for (int t = tid; t < V; t += 256) {
        int slot = (int)(s_key[t] & 1023u);
        sx1[t] = cx1[slot]; sy1[t] = cy1[slot];
        sx2[t] = cx2[slot]; sy2[t] = cy2[slot];
        sar[t] = car[slot];
    }
    __syncthreads();

    if (V <= 256) {
        // ---- Phase 3a: parallel IoU bit-matrix --------------------------
        const int BW = (V + 63) >> 6;
        for (int i = tid; i < V; i += 256) {
            float x1i = sx1[i], y1i = sy1[i], x2i = sx2[i], y2i = sy2[i];
            float ai  = sar[i];
            for (int w = 0; w < BW; ++w) {
                u64 mrow = 0;
                int j0 = w << 6;
                int j1 = min(V, j0 + 64);
                for (int j = max(j0, i + 1); j < j1; ++j) {
                    float lx = fmaxf(x1i, sx1[j]);
                    float ly = fmaxf(y1i, sy1[j]);
                    float rx = fminf(x2i, sx2[j]);
                    float ry = fminf(y2i, sy2[j]);
                    float iw = fmaxf(rx - lx, 0.0f);
                    float ih = fmaxf(ry - ly, 0.0f);
                    float inter = iw * ih;
                    float iou = inter / (ai + sar[j] - inter + 1e-9f);
                    if (iou > NMS_TH) mrow |= 1ull << (j - j0);
                }
                s_mask[(i << 2) + w] = mrow;
            }
        }
        __syncthreads();

        // ---- Phase 4a: greedy scan in registers (thread 0, no barriers) -
        if (tid == 0) {
            u64 r0 = 0, r1 = 0, r2 = 0, r3 = 0;
            u64 k0 = 0, k1 = 0, k2 = 0, k3 = 0;
            int kept = 0;
            for (int i = 0; i < V; ++i) {
                int w = i >> 6;
                u64 bit = 1ull << (i & 63);
                u64 rw = (w == 0) ? r0 : (w == 1) ? r1 : (w == 2) ? r2 : r3;
                if (rw & bit) continue;       // suppressed by earlier kept
                if (w == 0) k0 |= bit; else if (w == 1) k1 |= bit;
                else if (w == 2) k2 |= bit; else k3 |= bit;
                if (++kept >= TOPK) break;    // only top-100 are emitted
                const u64* mr = &s_mask[i << 2];
                r0 |= mr[0];
                if (BW > 1) r1 |= mr[1];
                if (BW > 2) r2 |= mr[2];
                if (BW > 3) r3 |= mr[3];
            }
            s_keep[0] = k0; s_keep[1] = k1; s_keep[2] = k2; s_keep[3] = k3;
        }
        __syncthreads();

        // ---- Phase 5a: parallel ranked output write ---------------------
        u64 kw0 = s_keep[0], kw1 = s_keep[1], kw2 = s_keep[2], kw3 = s_keep[3];
        for (int t = tid; t < V; t += 256) {
            int w = t >> 6;
            u64 kw = (w == 0) ? kw0 : (w == 1) ? kw1 : (w == 2) ? kw2 : kw3;
            if (!((kw >> (t & 63)) & 1ull)) continue;
            int rank = 0;
            if (w > 0) rank += __popcll(kw0);
            if (w > 1) rank += __popcll(kw1);
            if (w > 2) rank += __popcll(kw2);
            rank += __popcll(kw & ((1ull << (t & 63)) - 1ull));
            if (rank < TOPK) {
                float score = __uint_as_float((unsigned int)(s_key[t] >> 20));
                out[(c * TOPK + rank) * 4 + 0] = sx1[t];
                out[(c * TOPK + rank) * 4 + 1] = sy1[t];
                out[(c * TOPK + rank) * 4 + 2] = sx2[t];
                out[(c * TOPK + rank) * 4 + 3] = sy2[t];
                out[OFF_SCORES + c * TOPK + rank] = score;
                out[OFF_LABELS + c * TOPK + rank] = (float)col;
                out[OFF_VALID  + c * TOPK + rank] = 1.0f;
            }
        }
    } else {
        // ---- Fallback (V > 256, not hit by this data): barrier greedy ---
        for (int t = tid; t < V; t += 256) s_rem[t] = 0;
        __syncthreads();
        for (int i = 0; i < V; ++i) {
            if (s_rem[i]) continue;          // uniform LDS read, post-barrier
            if (tid == 0) {
                int k = s_emit;
                if (k < TOPK) {
                    float score = __uint_as_float((unsigned int)(s_key[i] >> 20));
                    out[(c * TOPK + k) * 4 + 0] = sx1[i];
                    out[(c * TOPK + k) * 4 + 1] = sy1[i];
                    out[(c * TOPK + k) * 4 + 2] = sx2[i];
                    out[(c * TOPK + k) * 4 + 3] = sy2[i];
                    out[OFF_SCORES + c * TOPK + k] = score;
                    out[OFF_LABELS + c * TOPK + k] = (float)col;
                    out[OFF_VALID  + c * TOPK + k] = 1.0f;
                }
                s_emit = k + 1;
            }
            float x1i = sx1[i], y1i = sy1[i], x2i = sx2[i], y2i = sy2[i];
            float ai  = sar[i];
            for (int jj = i + 1 + tid; jj < V; jj += 256) {
                if (s_rem[jj]) continue;
                float lx = fmaxf(x1i, sx1[jj]);
                float ly = fmaxf(y1i, sy1[jj]);
                float rx = fminf(x2i, sx2[jj]);
                float ry = fminf(y2i, sy2[jj]);
                float iw = fmaxf(rx - lx, 0.0f);
                float ih = fmaxf(ry - ly, 0.0f);
                float inter = iw * ih;
                float iou = inter / (ai + sar[jj] - inter + 1e-9f);
                if (iou > NMS_TH) s_rem[jj] = 1;
            }
            __syncthreads();
            if (s_emit >= TOPK) break;       // uniform read after barrier
        }
    }
}

extern "C" void kernel_launch(void* const* d_in, const int* in_sizes, int n_in,
                              void* d_out, int out_size, void* d_ws, size_t ws_size,
                              hipStream_t stream) {
    const float* class_logit = (const float*)d_in[0];   // [1000][81]
    const float* box_reg     = (const float*)d_in[1];   // [1000][324]
    const float* proposal    = (const float*)d_in[2];   // [1000][4]
    float* out = (float*)d_out;                         // 56000 floats
    (void)d_ws; (void)ws_size; (void)in_sizes; (void)n_in; (void)out_size;

    roihead_kernel<<<N_FG, 256, 0, stream>>>(class_logit, box_reg, proposal, out);
}

// Round 3
// 92.806 us; speedup vs baseline: 1.6406x; 1.5990x over previous
//
#include <hip/hip_runtime.h>
#include <math.h>

// Problem constants (from reference)
#define N_PROP   1000
#define C_ALL    81
#define N_FG     80
#define TOPK     100
#define CAP      1024        // max compacted entries
#define IMG_WH   800.0f
#define SCORE_TH 0.05f
#define NMS_TH   0.5f
#define MIN_SZ   1.0f
#define BBOX_CLIP 4.135166556742356f   // log(1000/16)

typedef unsigned long long u64;

// ---------------------------------------------------------------- kernel A
// One wave per proposal row: coalesced loads (lane k reads logit k),
// butterfly shfl reduction for rowmax and sum(exp(x-max)).
__global__ __launch_bounds__(256) void softmax_stats_kernel(
    const float* __restrict__ logits,   // [1000][81]
    float* __restrict__ smax,           // [1000]
    float* __restrict__ ssum)           // [1000]
{
    const int wave = threadIdx.x >> 6;
    const int lane = threadIdx.x & 63;
    const int n = blockIdx.x * 4 + wave;
    if (n >= N_PROP) return;
    const float* row = logits + n * C_ALL;

    float v1 = row[lane];                                  // lane < 64 < 81
    float v2 = (lane < C_ALL - 64) ? row[64 + lane] : 0.f; // lanes 0..16

    float m = (lane < C_ALL - 64) ? fmaxf(v1, v2) : v1;
    #pragma unroll
    for (int off = 32; off >= 1; off >>= 1)
        m = fmaxf(m, __shfl_xor(m, off, 64));

    float s = expf(v1 - m) + ((lane < C_ALL - 64) ? expf(v2 - m) : 0.0f);
    #pragma unroll
    for (int off = 32; off >= 1; off >>= 1)
        s += __shfl_xor(s, off, 64);

    if (lane == 0) { smax[n] = m; ssum[n] = s; }
}

// ---------------------------------------------------------------- kernel B
// One block per class: decode+filter+compact -> sort(V) -> bit-matrix NMS
// -> ranked top-100 write.
__global__ __launch_bounds__(256) void roihead_kernel(
    const float* __restrict__ logits,   // [1000][81]
    const float* __restrict__ boxreg,   // [1000][324]
    const float* __restrict__ prop,     // [1000][4]
    const float* __restrict__ smax,     // [1000]
    const float* __restrict__ ssum,     // [1000]
    float* __restrict__ out)            // 56000 floats
{
    __shared__ u64   s_key[CAP];
    __shared__ float cx1[CAP], cy1[CAP], cx2[CAP], cy2[CAP], car[CAP];
    __shared__ float sx1[CAP], sy1[CAP], sx2[CAP], sy2[CAP], sar[CAP];
    __shared__ u64   s_mask[256 * 4];
    __shared__ u64   s_keep[4];
    __shared__ unsigned char s_rem[CAP];
    __shared__ int   s_cnt, s_emit;

    const int c   = blockIdx.x;
    const int tid = threadIdx.x;
    const int col = c + 1;

    const int OFF_SCORES = N_FG * TOPK * 4;          // 32000
    const int OFF_LABELS = OFF_SCORES + N_FG * TOPK; // 40000
    const int OFF_VALID  = OFF_LABELS + N_FG * TOPK; // 48000

    // Zero this class's output slice (harness poisons d_out every call).
    for (int t = tid; t < TOPK * 4; t += 256) out[c * TOPK * 4 + t] = 0.0f;
    for (int t = tid; t < TOPK; t += 256) {
        out[OFF_SCORES + c * TOPK + t] = 0.0f;
        out[OFF_LABELS + c * TOPK + t] = 0.0f;
        out[OFF_VALID  + c * TOPK + t] = 0.0f;
    }
    if (tid == 0) { s_cnt = 0; s_emit = 0; }
    __syncthreads();

    // ---- Phase 1: score + decode + filter + compact ---------------------
    for (int n = tid; n < N_PROP; n += 256) {
        float score = expf(logits[n * C_ALL + col] - smax[n]) / ssum[n];

        float4 p = *(const float4*)(prop + n * 4);
        float w  = p.z - p.x;
        float h  = p.w - p.y;
        float pcx0 = p.x + 0.5f * w;
        float pcy0 = p.y + 0.5f * h;

        float4 d = *(const float4*)(boxreg + n * (C_ALL * 4) + col * 4);
        float dx = d.x / 10.0f;
        float dy = d.y / 10.0f;
        float dw = fminf(d.z / 5.0f, BBOX_CLIP);
        float dh = fminf(d.w / 5.0f, BBOX_CLIP);

        float pcx = dx * w + pcx0;
        float pcy = dy * h + pcy0;
        float pw  = expf(dw) * w;
        float ph  = expf(dh) * h;

        float x1 = fminf(fmaxf(pcx - 0.5f * pw, 0.0f), IMG_WH);
        float y1 = fminf(fmaxf(pcy - 0.5f * ph, 0.0f), IMG_WH);
        float x2 = fminf(fmaxf(pcx + 0.5f * pw, 0.0f), IMG_WH);
        float y2 = fminf(fmaxf(pcy + 0.5f * ph, 0.0f), IMG_WH);

        float bw = x2 - x1;
        float bh = y2 - y1;
        if (score >= SCORE_TH && bw >= MIN_SZ && bh >= MIN_SZ) {
            int slot = atomicAdd(&s_cnt, 1);
            // key: (score bits | 1023-idx | slot) -> descending-u64 sort
            // == (score desc, original index asc); idx unique so slot bits
            // never decide.
            unsigned int fb = __float_as_uint(score);
            s_key[slot] = ((u64)fb << 20) | ((u64)(1023 - n) << 10) | (u64)slot;
            cx1[slot] = x1; cy1[slot] = y1; cx2[slot] = x2; cy2[slot] = y2;
            car[slot] = bw * bh;
        }
    }
    __syncthreads();

    const int V = s_cnt;
    if (V == 0) return;                 // outputs already zeroed

    // ---- Phase 2: bitonic sort of V entries (pad to pow2 with key 0) ----
    int VP2 = 1; while (VP2 < V) VP2 <<= 1;
    for (int t = V + tid; t < VP2; t += 256) s_key[t] = 0ull;
    __syncthreads();

    for (int k = 2; k <= VP2; k <<= 1) {
        for (int j = k >> 1; j > 0; j >>= 1) {
            for (int i = tid; i < VP2; i += 256) {
                int ixj = i ^ j;
                if (ixj > i) {
                    u64 a = s_key[i], b = s_key[ixj];
                    bool dir = ((i & k) == 0);
                    if ((b > a) == dir) { s_key[i] = b; s_key[ixj] = a; }
                }
            }
            __syncthreads();
        }
    }

    // Gather coords into sorted order.
    for (int t = tid; t < V; t += 256) {
        int slot = (int)(s_key[t] & 1023u);
        sx1[t] = cx1[slot]; sy1[t] = cy1[slot];
        sx2[t] = cx2[slot]; sy2[t] = cy2[slot];
        sar[t] = car[slot];
    }
    __syncthreads();

    if (V <= 256) {
        // ---- Phase 3a: parallel IoU bit-matrix --------------------------
        const int BW = (V + 63) >> 6;
        for (int i = tid; i < V; i += 256) {
            float x1i = sx1[i], y1i = sy1[i], x2i = sx2[i], y2i = sy2[i];
            float ai  = sar[i];
            for (int w = 0; w < BW; ++w) {
                u64 mrow = 0;
                int j0 = w << 6;
                int j1 = min(V, j0 + 64);
                for (int j = max(j0, i + 1); j < j1; ++j) {
                    float lx = fmaxf(x1i, sx1[j]);
                    float ly = fmaxf(y1i, sy1[j]);
                    float rx = fminf(x2i, sx2[j]);
                    float ry = fminf(y2i, sy2[j]);
                    float iw = fmaxf(rx - lx, 0.0f);
                    float ih = fmaxf(ry - ly, 0.0f);
                    float inter = iw * ih;
                    float iou = inter / (ai + sar[j] - inter + 1e-9f);
                    if (iou > NMS_TH) mrow |= 1ull << (j - j0);
                }
                s_mask[(i << 2) + w] = mrow;
            }
        }
        __syncthreads();

        // ---- Phase 4a: greedy scan in registers (thread 0, no barriers) -
        if (tid == 0) {
            u64 r0 = 0, r1 = 0, r2 = 0, r3 = 0;
            u64 k0 = 0, k1 = 0, k2 = 0, k3 = 0;
            int kept = 0;
            for (int i = 0; i < V; ++i) {
                int w = i >> 6;
                u64 bit = 1ull << (i & 63);
                u64 rw = (w == 0) ? r0 : (w == 1) ? r1 : (w == 2) ? r2 : r3;
                if (rw & bit) continue;
                if (w == 0) k0 |= bit; else if (w == 1) k1 |= bit;
                else if (w == 2) k2 |= bit; else k3 |= bit;
                if (++kept >= TOPK) break;
                const u64* mr = &s_mask[i << 2];
                r0 |= mr[0];
                if (BW > 1) r1 |= mr[1];
                if (BW > 2) r2 |= mr[2];
                if (BW > 3) r3 |= mr[3];
            }
            s_keep[0] = k0; s_keep[1] = k1; s_keep[2] = k2; s_keep[3] = k3;
        }
        __syncthreads();

        // ---- Phase 5a: parallel ranked output write ---------------------
        u64 kw0 = s_keep[0], kw1 = s_keep[1], kw2 = s_keep[2], kw3 = s_keep[3];
        for (int t = tid; t < V; t += 256) {
            int w = t >> 6;
            u64 kw = (w == 0) ? kw0 : (w == 1) ? kw1 : (w == 2) ? kw2 : kw3;
            if (!((kw >> (t & 63)) & 1ull)) continue;
            int rank = 0;
            if (w > 0) rank += __popcll(kw0);
            if (w > 1) rank += __popcll(kw1);
            if (w > 2) rank += __popcll(kw2);
            rank += __popcll(kw & ((1ull << (t & 63)) - 1ull));
            if (rank < TOPK) {
                float score = __uint_as_float((unsigned int)(s_key[t] >> 20));
                out[(c * TOPK + rank) * 4 + 0] = sx1[t];
                out[(c * TOPK + rank) * 4 + 1] = sy1[t];
                out[(c * TOPK + rank) * 4 + 2] = sx2[t];
                out[(c * TOPK + rank) * 4 + 3] = sy2[t];
                out[OFF_SCORES + c * TOPK + rank] = score;
                out[OFF_LABELS + c * TOPK + rank] = (float)col;
                out[OFF_VALID  + c * TOPK + rank] = 1.0f;
            }
        }
    } else {
        // ---- Fallback (V > 256): barrier greedy -------------------------
        for (int t = tid; t < V; t += 256) s_rem[t] = 0;
        __syncthreads();
        for (int i = 0; i < V; ++i) {
            if (s_rem[i]) continue;          // uniform LDS read, post-barrier
            if (tid == 0) {
                int k = s_emit;
                if (k < TOPK) {
                    float score = __uint_as_float((unsigned int)(s_key[i] >> 20));
                    out[(c * TOPK + k) * 4 + 0] = sx1[i];
                    out[(c * TOPK + k) * 4 + 1] = sy1[i];
                    out[(c * TOPK + k) * 4 + 2] = sx2[i];
                    out[(c * TOPK + k) * 4 + 3] = sy2[i];
                    out[OFF_SCORES + c * TOPK + k] = score;
                    out[OFF_LABELS + c * TOPK + k] = (float)col;
                    out[OFF_VALID  + c * TOPK + k] = 1.0f;
                }
                s_emit = k + 1;
            }
            float x1i = sx1[i], y1i = sy1[i], x2i = sx2[i], y2i = sy2[i];
            float ai  = sar[i];
            for (int jj = i + 1 + tid; jj < V; jj += 256) {
                if (s_rem[jj]) continue;
                float lx = fmaxf(x1i, sx1[jj]);
                float ly = fmaxf(y1i, sy1[jj]);
                float rx = fminf(x2i, sx2[jj]);
                float ry = fminf(y2i, sy2[jj]);
                float iw = fmaxf(rx - lx, 0.0f);
                float ih = fmaxf(ry - ly, 0.0f);
                float inter = iw * ih;
                float iou = inter / (ai + sar[jj] - inter + 1e-9f);
                if (iou > NMS_TH) s_rem[jj] = 1;
            }
            __syncthreads();
            if (s_emit >= TOPK) break;       // uniform read after barrier
        }
    }
}

extern "C" void kernel_launch(void* const* d_in, const int* in_sizes, int n_in,
                              void* d_out, int out_size, void* d_ws, size_t ws_size,
                              hipStream_t stream) {
    const float* class_logit = (const float*)d_in[0];   // [1000][81]
    const float* box_reg     = (const float*)d_in[1];   // [1000][324]
    const float* proposal    = (const float*)d_in[2];   // [1000][4]
    float* out = (float*)d_out;                         // 56000 floats

    float* ws   = (float*)d_ws;
    float* smax = ws;               // 1000
    float* ssum = smax + N_PROP;    // 1000

    softmax_stats_kernel<<<(N_PROP + 3) / 4, 256, 0, stream>>>(class_logit, smax, ssum);
    roihead_kernel<<<N_FG, 256, 0, stream>>>(class_logit, box_reg, proposal,
                                             smax, ssum, out);
}

// Round 4
// 87.875 us; speedup vs baseline: 1.7327x; 1.0561x over previous
//
#include <hip/hip_runtime.h>
#include <math.h>

// Problem constants (from reference)
#define N_PROP   1000
#define C_ALL    81
#define N_FG     80
#define TOPK     100
#define CAP      1024        // max compacted entries
#define IMG_WH   800.0f
#define SCORE_TH 0.05f
#define NMS_TH   0.5f
#define MIN_SZ   1.0f
#define BBOX_CLIP 4.135166556742356f   // log(1000/16)

typedef unsigned long long u64;

// ---------------------------------------------------------------- kernel A
// One wave per proposal row: coalesced loads, butterfly shfl reduction.
// Writes (max, sum) packed as float2 for a single 8B load downstream.
__global__ __launch_bounds__(256) void softmax_stats_kernel(
    const float* __restrict__ logits,   // [1000][81]
    float2* __restrict__ stats)         // [1000] (rowmax, rowsum)
{
    const int wave = threadIdx.x >> 6;
    const int lane = threadIdx.x & 63;
    const int n = blockIdx.x * 4 + wave;
    if (n >= N_PROP) return;
    const float* row = logits + n * C_ALL;

    float v1 = row[lane];
    float v2 = (lane < C_ALL - 64) ? row[64 + lane] : 0.f;

    float m = (lane < C_ALL - 64) ? fmaxf(v1, v2) : v1;
    #pragma unroll
    for (int off = 32; off >= 1; off >>= 1)
        m = fmaxf(m, __shfl_xor(m, off, 64));

    float s = expf(v1 - m) + ((lane < C_ALL - 64) ? expf(v2 - m) : 0.0f);
    #pragma unroll
    for (int off = 32; off >= 1; off >>= 1)
        s += __shfl_xor(s, off, 64);

    if (lane == 0) stats[n] = make_float2(m, s);
}

// ---------------------------------------------------------------- kernel B
// One block per class: decode+filter+compact -> rank-sort (1 barrier) ->
// NMS (wave-resident for V<=64, bit-matrix for V<=256, barrier fallback).
__global__ __launch_bounds__(256) void roihead_kernel(
    const float* __restrict__ logits,   // [1000][81]
    const float* __restrict__ boxreg,   // [1000][324]
    const float* __restrict__ prop,     // [1000][4]
    const float2* __restrict__ stats,   // [1000]
    float* __restrict__ out)            // 56000 floats
{
    __shared__ u64   s_key[CAP];                    // compaction order
    __shared__ float cx1[CAP], cy1[CAP], cx2[CAP], cy2[CAP], car[CAP];
    __shared__ u64   s_skey[CAP];                   // sorted order
    __shared__ float sx1[CAP], sy1[CAP], sx2[CAP], sy2[CAP], sar[CAP];
    __shared__ u64   s_mask[256 * 4];
    __shared__ u64   s_keep[4];
    __shared__ unsigned char s_rem[CAP];
    __shared__ int   s_cnt, s_emit;

    const int c   = blockIdx.x;
    const int tid = threadIdx.x;
    const int col = c + 1;

    const int OFF_SCORES = N_FG * TOPK * 4;          // 32000
    const int OFF_LABELS = OFF_SCORES + N_FG * TOPK; // 40000
    const int OFF_VALID  = OFF_LABELS + N_FG * TOPK; // 48000

    // Zero this class's output slice (harness poisons d_out every call).
    for (int t = tid; t < TOPK * 4; t += 256) out[c * TOPK * 4 + t] = 0.0f;
    for (int t = tid; t < TOPK; t += 256) {
        out[OFF_SCORES + c * TOPK + t] = 0.0f;
        out[OFF_LABELS + c * TOPK + t] = 0.0f;
        out[OFF_VALID  + c * TOPK + t] = 0.0f;
    }
    if (tid == 0) { s_cnt = 0; s_emit = 0; }
    __syncthreads();

    // ---- Phase 1: score + decode + filter + compact ---------------------
    for (int n = tid; n < N_PROP; n += 256) {
        float2 ms = stats[n];
        float score = expf(logits[n * C_ALL + col] - ms.x) / ms.y;

        float4 p = *(const float4*)(prop + n * 4);
        float w  = p.z - p.x;
        float h  = p.w - p.y;
        float pcx0 = p.x + 0.5f * w;
        float pcy0 = p.y + 0.5f * h;

        float4 d = *(const float4*)(boxreg + n * (C_ALL * 4) + col * 4);
        float dx = d.x / 10.0f;
        float dy = d.y / 10.0f;
        float dw = fminf(d.z / 5.0f, BBOX_CLIP);
        float dh = fminf(d.w / 5.0f, BBOX_CLIP);

        float pcx = dx * w + pcx0;
        float pcy = dy * h + pcy0;
        float pw  = expf(dw) * w;
        float ph  = expf(dh) * h;

        float x1 = fminf(fmaxf(pcx - 0.5f * pw, 0.0f), IMG_WH);
        float y1 = fminf(fmaxf(pcy - 0.5f * ph, 0.0f), IMG_WH);
        float x2 = fminf(fmaxf(pcx + 0.5f * pw, 0.0f), IMG_WH);
        float y2 = fminf(fmaxf(pcy + 0.5f * ph, 0.0f), IMG_WH);

        float bw = x2 - x1;
        float bh = y2 - y1;
        if (score >= SCORE_TH && bw >= MIN_SZ && bh >= MIN_SZ) {
            int slot = atomicAdd(&s_cnt, 1);
            // key: (score bits | 1023-idx | slot) -> descending-u64 order
            // == (score desc, original index asc); idx bits make keys unique.
            unsigned int fb = __float_as_uint(score);
            s_key[slot] = ((u64)fb << 20) | ((u64)(1023 - n) << 10) | (u64)slot;
            cx1[slot] = x1; cy1[slot] = y1; cx2[slot] = x2; cy2[slot] = y2;
            car[slot] = bw * bh;
        }
    }
    __syncthreads();

    const int V = s_cnt;
    if (V == 0) return;                 // outputs already zeroed

    // ---- Phase 2: rank sort (keys unique -> ranks unique) ---------------
    // Inner reads are same-address across threads -> LDS broadcast.
    for (int t = tid; t < V; t += 256) {
        u64 myk = s_key[t];
        int rank = 0;
        for (int j = 0; j < V; ++j) rank += (s_key[j] > myk) ? 1 : 0;
        s_skey[rank] = myk;
        sx1[rank] = cx1[t]; sy1[rank] = cy1[t];
        sx2[rank] = cx2[t]; sy2[rank] = cy2[t];
        sar[rank] = car[t];
    }
    __syncthreads();

    if (V <= 64) {
        // ---- Wave-resident NMS: lane j holds sorted box j ---------------
        if (tid < 64) {
            const int lane = tid;
            bool act = lane < V;
            float bx1 = 0.f, by1 = 0.f, bx2 = 0.f, by2 = 0.f, bar = 0.f;
            if (act) {
                bx1 = sx1[lane]; by1 = sy1[lane];
                bx2 = sx2[lane]; by2 = sy2[lane];
                bar = sar[lane];
            }
            u64 myrow = 0;   // suppression row i (held by lane i)
            for (int i = 0; i < V; ++i) {
                float ix1 = __shfl(bx1, i, 64);
                float iy1 = __shfl(by1, i, 64);
                float ix2 = __shfl(bx2, i, 64);
                float iy2 = __shfl(by2, i, 64);
                float iar = __shfl(bar, i, 64);
                float lx = fmaxf(ix1, bx1);
                float ly = fmaxf(iy1, by1);
                float rx = fminf(ix2, bx2);
                float ry = fminf(iy2, by2);
                float iw = fmaxf(rx - lx, 0.0f);
                float ih = fmaxf(ry - ly, 0.0f);
                float inter = iw * ih;
                float iou = inter / (iar + bar - inter + 1e-9f);
                u64 bal = __ballot(act && (iou > NMS_TH));
                if (lane == i) {
                    // only j > i can be suppressed by i
                    u64 upper = (i == 63) ? 0ull : ~((1ull << (i + 1)) - 1ull);
                    myrow = bal & upper;
                }
            }
            // Greedy scan at shfl latency; all state wave-uniform.
            u64 S = 0, K = 0;
            for (int i = 0; i < V; ++i) {
                if (!((S >> i) & 1ull)) {
                    K |= 1ull << i;
                    S |= __shfl(myrow, i, 64);
                }
            }
            // V <= 64 < TOPK: every kept box is emitted, rank = popcount below.
            if (act && ((K >> lane) & 1ull)) {
                int rank = __popcll(K & ((1ull << lane) - 1ull));
                float score = __uint_as_float((unsigned int)(s_skey[lane] >> 20));
                out[(c * TOPK + rank) * 4 + 0] = bx1;
                out[(c * TOPK + rank) * 4 + 1] = by1;
                out[(c * TOPK + rank) * 4 + 2] = bx2;
                out[(c * TOPK + rank) * 4 + 3] = by2;
                out[OFF_SCORES + c * TOPK + rank] = score;
                out[OFF_LABELS + c * TOPK + rank] = (float)col;
                out[OFF_VALID  + c * TOPK + rank] = 1.0f;
            }
        }
    } else if (V <= 256) {
        // ---- Bit-matrix NMS -----------------------------------------
        const int BW = (V + 63) >> 6;
        for (int i = tid; i < V; i += 256) {
            float x1i = sx1[i], y1i = sy1[i], x2i = sx2[i], y2i = sy2[i];
            float ai  = sar[i];
            for (int w = 0; w < BW; ++w) {
                u64 mrow = 0;
                int j0 = w << 6;
                int j1 = min(V, j0 + 64);
                for (int j = max(j0, i + 1); j < j1; ++j) {
                    float lx = fmaxf(x1i, sx1[j]);
                    float ly = fmaxf(y1i, sy1[j]);
                    float rx = fminf(x2i, sx2[j]);
                    float ry = fminf(y2i, sy2[j]);
                    float iw = fmaxf(rx - lx, 0.0f);
                    float ih = fmaxf(ry - ly, 0.0f);
                    float inter = iw * ih;
                    float iou = inter / (ai + sar[j] - inter + 1e-9f);
                    if (iou > NMS_TH) mrow |= 1ull << (j - j0);
                }
                s_mask[(i << 2) + w] = mrow;
            }
        }
        __syncthreads();

        if (tid == 0) {
            u64 r0 = 0, r1 = 0, r2 = 0, r3 = 0;
            u64 k0 = 0, k1 = 0, k2 = 0, k3 = 0;
            int kept = 0;
            for (int i = 0; i < V; ++i) {
                int w = i >> 6;
                u64 bit = 1ull << (i & 63);
                u64 rw = (w == 0) ? r0 : (w == 1) ? r1 : (w == 2) ? r2 : r3;
                if (rw & bit) continue;
                if (w == 0) k0 |= bit; else if (w == 1) k1 |= bit;
                else if (w == 2) k2 |= bit; else k3 |= bit;
                if (++kept >= TOPK) break;
                const u64* mr = &s_mask[i << 2];
                r0 |= mr[0];
                if (BW > 1) r1 |= mr[1];
                if (BW > 2) r2 |= mr[2];
                if (BW > 3) r3 |= mr[3];
            }
            s_keep[0] = k0; s_keep[1] = k1; s_keep[2] = k2; s_keep[3] = k3;
        }
        __syncthreads();

        u64 kw0 = s_keep[0], kw1 = s_keep[1], kw2 = s_keep[2], kw3 = s_keep[3];
        for (int t = tid; t < V; t += 256) {
            int w = t >> 6;
            u64 kw = (w == 0) ? kw0 : (w == 1) ? kw1 : (w == 2) ? kw2 : kw3;
            if (!((kw >> (t & 63)) & 1ull)) continue;
            int rank = 0;
            if (w > 0) rank += __popcll(kw0);
            if (w > 1) rank += __popcll(kw1);
            if (w > 2) rank += __popcll(kw2);
            rank += __popcll(kw & ((1ull << (t & 63)) - 1ull));
            if (rank < TOPK) {
                float score = __uint_as_float((unsigned int)(s_skey[t] >> 20));
                out[(c * TOPK + rank) * 4 + 0] = sx1[t];
                out[(c * TOPK + rank) * 4 + 1] = sy1[t];
                out[(c * TOPK + rank) * 4 + 2] = sx2[t];
                out[(c * TOPK + rank) * 4 + 3] = sy2[t];
                out[OFF_SCORES + c * TOPK + rank] = score;
                out[OFF_LABELS + c * TOPK + rank] = (float)col;
                out[OFF_VALID  + c * TOPK + rank] = 1.0f;
            }
        }
    } else {
        // ---- Fallback (V > 256): barrier greedy -------------------------
        for (int t = tid; t < V; t += 256) s_rem[t] = 0;
        __syncthreads();
        for (int i = 0; i < V; ++i) {
            if (s_rem[i]) continue;
            if (tid == 0) {
                int k = s_emit;
                if (k < TOPK) {
                    float score = __uint_as_float((unsigned int)(s_skey[i] >> 20));
                    out[(c * TOPK + k) * 4 + 0] = sx1[i];
                    out[(c * TOPK + k) * 4 + 1] = sy1[i];
                    out[(c * TOPK + k) * 4 + 2] = sx2[i];
                    out[(c * TOPK + k) * 4 + 3] = sy2[i];
                    out[OFF_SCORES + c * TOPK + k] = score;
                    out[OFF_LABELS + c * TOPK + k] = (float)col;
                    out[OFF_VALID  + c * TOPK + k] = 1.0f;
                }
                s_emit = k + 1;
            }
            float x1i = sx1[i], y1i = sy1[i], x2i = sx2[i], y2i = sy2[i];
            float ai  = sar[i];
            for (int jj = i + 1 + tid; jj < V; jj += 256) {
                if (s_rem[jj]) continue;
                float lx = fmaxf(x1i, sx1[jj]);
                float ly = fmaxf(y1i, sy1[jj]);
                float rx = fminf(x2i, sx2[jj]);
                float ry = fminf(y2i, sy2[jj]);
                float iw = fmaxf(rx - lx, 0.0f);
                float ih = fmaxf(ry - ly, 0.0f);
                float inter = iw * ih;
                float iou = inter / (ai + sar[jj] - inter + 1e-9f);
                if (iou > NMS_TH) s_rem[jj] = 1;
            }
            __syncthreads();
            if (s_emit >= TOPK) break;
        }
    }
}

extern "C" void kernel_launch(void* const* d_in, const int* in_sizes, int n_in,
                              void* d_out, int out_size, void* d_ws, size_t ws_size,
                              hipStream_t stream) {
    const float* class_logit = (const float*)d_in[0];   // [1000][81]
    const float* box_reg     = (const float*)d_in[1];   // [1000][324]
    const float* proposal    = (const float*)d_in[2];   // [1000][4]
    float* out = (float*)d_out;                         // 56000 floats

    float2* stats = (float2*)d_ws;      // 1000 x (max, sum)

    softmax_stats_kernel<<<(N_PROP + 3) / 4, 256, 0, stream>>>(class_logit, stats);
    roihead_kernel<<<N_FG, 256, 0, stream>>>(class_logit, box_reg, proposal,
                                             stats, out);
}